// Round 18
// baseline (185.345 us; speedup 1.0000x reference)
//
#include <hip/hip_runtime.h>
#include <hip/hip_bf16.h>

#define Bc 16
#define Nc 512
#define Dc 768
#define Hc 12
#define Ec 8
#define HDc 64
#define D3 (3 * Dc)   // 2304
#define ZS ((size_t)Bc * Hc * Nc * HDc)   // per-tensor compact size: 192*512*64

// prep kernel block ranges
#define NBW  (Dc * Dc / 4 / 256)          // 576 blocks per weight tensor
#define NBB  (Bc * Dc / 256)              // 48
#define NBWO (Dc * Dc / 8 / 256)          // 288
#define NBX  (Bc * Nc * Dc / 8 / 256)     // 3072

typedef __hip_bfloat16 bf16;
typedef short bf16x8 __attribute__((ext_vector_type(8)));     // 8 bf16, 4 VGPR
typedef float f32x4 __attribute__((ext_vector_type(4)));
typedef unsigned short u16x4 __attribute__((ext_vector_type(4)));

__device__ __forceinline__ unsigned int f2bf(float f) {
    union { __hip_bfloat16 h; unsigned short u; } cv;
    cv.h = __float2bfloat16(f);
    return (unsigned int)cv.u;
}

__device__ __forceinline__ void gload16(const void* src, void* ldsDst) {
    __builtin_amdgcn_global_load_lds((const __attribute__((address_space(1))) void*)src,
                                     (__attribute__((address_space(3))) void*)ldsDst,
                                     16, 0, 0);
}

// ---------------- merged prologue: combine_w (x3) | combine_b | cast Wo | cast x ----------------
// R18: all input streams are read-once -> NONTEMPORAL loads (no L2 pollution);
// Wc (37.7MB > L2) written nontemporally; x_bf/Wo_bf stay cacheable (re-read soon).
__global__ __launch_bounds__(256) void prep_kernel(const float* __restrict__ g,
                                                   const float* __restrict__ W0,
                                                   const float* __restrict__ W1,
                                                   const float* __restrict__ W2,
                                                   const float* __restrict__ b0,
                                                   const float* __restrict__ b1,
                                                   const float* __restrict__ b2,
                                                   const float* __restrict__ Wo,
                                                   const float* __restrict__ x,
                                                   bf16* __restrict__ Wc,
                                                   float* __restrict__ bc,
                                                   bf16* __restrict__ Wo_bf,
                                                   bf16* __restrict__ x_bf) {
    __shared__ float gs[Bc * Ec];
    int blk = blockIdx.x, tid = threadIdx.x;
    if (blk < 3 * NBW) {
        // ---- gating fold: Wc[b][t*768+o][i] = sum_e g[b,e] W[e][o][i] ----
        if (tid < Bc * Ec) gs[tid] = g[tid];
        __syncthreads();
        int t = blk / NBW;
        const float* W = (t == 0) ? W0 : ((t == 1) ? W1 : W2);
        int p = (blk - t * NBW) * 256 + tid;     // float4 position
        f32x4 w[Ec];
#pragma unroll
        for (int e = 0; e < Ec; ++e)
            w[e] = __builtin_nontemporal_load((const f32x4*)W + (size_t)e * (Dc * Dc / 4) + p);
        int o = p / (Dc / 4), i4 = p - o * (Dc / 4);
#pragma unroll
        for (int b = 0; b < Bc; ++b) {
            f32x4 acc = {0.f, 0.f, 0.f, 0.f};
#pragma unroll
            for (int e = 0; e < Ec; ++e) {
                float ge = gs[b * Ec + e];
                acc[0] += ge * w[e][0]; acc[1] += ge * w[e][1];
                acc[2] += ge * w[e][2]; acc[3] += ge * w[e][3];
            }
            u16x4 ov;
#pragma unroll
            for (int j = 0; j < 4; ++j) ov[j] = (unsigned short)f2bf(acc[j]);
            __builtin_nontemporal_store(ov,
                (u16x4*)&Wc[((size_t)b * D3 + t * Dc + o) * Dc + i4 * 4]);
        }
    } else if (blk < 3 * NBW + NBB) {
        // ---- bias fold (all three tensors per thread) ----
        int i = (blk - 3 * NBW) * 256 + tid;     // 0..Bc*Dc-1
        int b = i / Dc, o = i - b * Dc;
        const float* bs[3] = {b0, b1, b2};
#pragma unroll
        for (int t = 0; t < 3; ++t) {
            float acc = 0.f;
#pragma unroll
            for (int e = 0; e < Ec; ++e) acc += g[b * Ec + e] * bs[t][e * Dc + o];
            bc[(size_t)b * D3 + t * Dc + o] = acc;
        }
    } else if (blk < 3 * NBW + NBB + NBWO) {
        // ---- cast Wo -> bf16 ----
        int i = (blk - 3 * NBW - NBB) * 256 + tid;
        f32x4 a = __builtin_nontemporal_load((const f32x4*)Wo + i * 2);
        f32x4 b = __builtin_nontemporal_load((const f32x4*)Wo + i * 2 + 1);
        unsigned short t[8];
#pragma unroll
        for (int j = 0; j < 4; ++j) { t[j] = (unsigned short)f2bf(a[j]); t[4 + j] = (unsigned short)f2bf(b[j]); }
        ((bf16x8*)Wo_bf)[i] = *(bf16x8*)t;
    } else {
        // ---- cast x -> bf16 ----
        int i = (blk - 3 * NBW - NBB - NBWO) * 256 + tid;
        f32x4 a = __builtin_nontemporal_load((const f32x4*)x + i * 2);
        f32x4 b = __builtin_nontemporal_load((const f32x4*)x + i * 2 + 1);
        unsigned short t[8];
#pragma unroll
        for (int j = 0; j < 4; ++j) { t[j] = (unsigned short)f2bf(a[j]); t[4 + j] = (unsigned short)f2bf(b[j]); }
        ((bf16x8*)x_bf)[i] = *(bf16x8*)t;
    }
}

// ---------------- bf16 MFMA NT GEMM: C[z] = A[z] * B[z]^T (+ bias) ----------------
// R15 structure: 4 waves (2x2), tile BM x BN, BK=64 single-buffered (two 32-wide
// sub-steps per barrier pair). Grid 1-D XCD-SWIZZLED: 8 XCDs x 2 z x (NBN*NBM).
// OMODE 0: f32 output with ldc (+bias), nontemporal (write-once stream).
// OMODE 1: QKV split output -> Cout is Qz base. Q (cols<768, pre-scaled 1/8) and
//          K (768..1535) go compact [z*H+h][row][64]; V (>=1536) is written DIRECTLY
//          in Vp fragment order at +2ZS (one uint2 per m-tile).
template<int BM, int BN, int OMODE, int NBN, int NBM>
__global__ __launch_bounds__(256) void gemm_mfma(const bf16* __restrict__ Ain,
                                                 const bf16* __restrict__ Bin,
                                                 void* __restrict__ Cout,
                                                 const float* __restrict__ bias,
                                                 int lda, int ldb, int ldc, int K,
                                                 long sA, long sB, long sC, int sBias) {
    constexpr int A_LDS = BM * 128;   // two 32-col halves of BM*64 bytes each
    constexpr int B_LDS = BN * 128;
    __shared__ __align__(16) char lds[A_LDS + B_LDS];
    char* ldsA = lds;
    char* ldsB = lds + A_LDS;

    const int tid = threadIdx.x;
    const int lane = tid & 63;
    const int wave = tid >> 6;
    const int wr = wave >> 1, wc = wave & 1;
    constexpr int TM = BM / 32;
    constexpr int TN = BN / 32;

    // XCD swizzle: consecutive blockIdx round-robin XCDs (L&7).
    constexpr int PERZ = NBN * NBM;
    int L = blockIdx.x;
    int xcd = L & 7, i = L >> 3;
    int zi = (i >= PERZ) ? 1 : 0;
    const int z = xcd * 2 + zi;
    int j = i - zi * PERZ;
    const int n0 = (j % NBN) * BN;
    const int m0 = (j / NBN) * BM;

    const int mbase = wr * (BM / 2);
    const int nbase = wc * (BN / 2);

    const bf16* Ab = Ain + (size_t)z * sA;
    const bf16* Bb = Bin + (size_t)z * sB;

    f32x4 acc[TM][TN];
#pragma unroll
    for (int m = 0; m < TM; ++m)
#pragma unroll
        for (int n = 0; n < TN; ++n) acc[m][n] = f32x4{0.f, 0.f, 0.f, 0.f};

    constexpr int ACH = BM / 64;   // 1024B chunks per wave per half
    constexpr int BCH = BN / 64;

    for (int k0 = 0; k0 < K; k0 += 64) {
        // ---- stage A tile (both 32-col halves) ----
#pragma unroll
        for (int hh = 0; hh < 2; ++hh)
#pragma unroll
            for (int c = 0; c < ACH; ++c) {
                int q = wave * ACH + c;
                int row = q * 16 + (lane >> 2);
                int sl = (lane & 3) ^ (row & 3);
                const bf16* src = Ab + (size_t)(m0 + row) * lda + k0 + hh * 32 + sl * 8;
                gload16(src, ldsA + hh * (BM * 64) + q * 1024);
            }
        // ---- stage B tile ----
#pragma unroll
        for (int hh = 0; hh < 2; ++hh)
#pragma unroll
            for (int c = 0; c < BCH; ++c) {
                int q = wave * BCH + c;
                int row = q * 16 + (lane >> 2);
                int sl = (lane & 3) ^ (row & 3);
                const bf16* src = Bb + (size_t)(n0 + row) * ldb + k0 + hh * 32 + sl * 8;
                gload16(src, ldsB + hh * (BN * 64) + q * 1024);
            }
        __syncthreads();

#pragma unroll
        for (int hh = 0; hh < 2; ++hh) {
            bf16x8 af[TM], bfr[TN];
#pragma unroll
            for (int m = 0; m < TM; ++m) {
                int r = mbase + m * 16 + (lane & 15);
                int sp = (lane >> 4) ^ (lane & 3);       // == (lane>>4) ^ (r&3)
                af[m] = *(const bf16x8*)(ldsA + hh * (BM * 64) + r * 64 + sp * 16);
            }
#pragma unroll
            for (int n = 0; n < TN; ++n) {
                int r = nbase + n * 16 + (lane & 15);
                int sp = (lane >> 4) ^ (lane & 3);
                bfr[n] = *(const bf16x8*)(ldsB + hh * (BN * 64) + r * 64 + sp * 16);
            }
#pragma unroll
            for (int m = 0; m < TM; ++m)
#pragma unroll
                for (int n = 0; n < TN; ++n)
                    acc[m][n] = __builtin_amdgcn_mfma_f32_16x16x32_bf16(af[m], bfr[n], acc[m][n], 0, 0, 0);
        }
        __syncthreads();
    }

    // ---- epilogue ----
#pragma unroll
    for (int n = 0; n < TN; ++n) {
        int colbase = n0 + nbase + n * 16;
        int col = colbase + (lane & 15);
        float bv = bias ? bias[(size_t)z * sBias + col] : 0.f;
        if constexpr (OMODE == 1) {
            int t = colbase / Dc;                  // 0=Q 1=K 2=V (16-col group never crosses)
            int within = colbase - t * Dc;
            int h = within >> 6;
            int dbase = within & 63;
            if (t == 2) {
                // direct Vp fragment write: one uint2 per m-tile
                bf16* vp = (bf16*)Cout + 2 * ZS
                         + (((size_t)(z * Hc + h) * 16) * 4 + (dbase >> 4)) * 512
                         + (size_t)lane * 8;
#pragma unroll
                for (int m = 0; m < TM; ++m) {
                    int rowblk = m0 + mbase + m * 16;
                    int c = rowblk >> 5, jb = (rowblk >> 4) & 1;
                    uint2 wv = {f2bf(acc[m][n][0] + bv) | (f2bf(acc[m][n][1] + bv) << 16),
                                f2bf(acc[m][n][2] + bv) | (f2bf(acc[m][n][3] + bv) << 16)};
                    *(uint2*)(vp + (size_t)c * 2048 + jb * 4) = wv;
                }
            } else {
                float qs = (t == 0) ? 0.125f : 1.0f;
                bf16* dst = (bf16*)Cout + (size_t)t * ZS
                          + ((size_t)(z * Hc + h) * Nc) * HDc + dbase + (lane & 15);
#pragma unroll
                for (int m = 0; m < TM; ++m) {
                    int row = m0 + mbase + m * 16 + (lane >> 4) * 4;
#pragma unroll
                    for (int r = 0; r < 4; ++r)
                        dst[(size_t)(row + r) * HDc] = __float2bfloat16((acc[m][n][r] + bv) * qs);
                }
            }
        } else {
            size_t cOff = (size_t)z * sC;
#pragma unroll
            for (int m = 0; m < TM; ++m) {
                int row = m0 + mbase + m * 16 + (lane >> 4) * 4;
#pragma unroll
                for (int r = 0; r < 4; ++r)
                    __builtin_nontemporal_store(acc[m][n][r] + bv,
                        &((float*)Cout)[cOff + (size_t)(row + r) * ldc + col]);
            }
        }
    }
}

// ---------------- fused: attn[z] = softmax(Q' K^T) -> d_out; ctx = attn @ V ----------------
// Q' carries the 1/8 scale. Block = 4 waves, TWO 16-row q-tiles; k SPLIT ACROSS WAVES.
// Single-barrier flash-style combine; 12-fragment Vp prefetch across the barrier
// (R18: widened from 8); attn NT stores between combine and PV; setprio around
// both MFMA clusters (T5, phase-split schedule).
__global__ __launch_bounds__(256) void fused_attn_kernel(const bf16* __restrict__ Qz,
                                                         const bf16* __restrict__ Kz,
                                                         const bf16* __restrict__ Vp,
                                                         float* __restrict__ attn,
                                                         bf16* __restrict__ ctx) {
    __shared__ float msum[2][2][4][16];              // [m|sum][tile][src wave][row]
    __shared__ __align__(16) char plds[2][16][1024]; // per-tile P: 16 rows x 512 k bf16

    int L = blockIdx.x;                   // 0..3071; L%8 == z%8 -> one XCD per head
    int z = (L & 7) + 8 * (L >> 7);
    int qt = (L >> 3) & 15;
    int b = z / Hc, h = z - b * Hc;
    int wave = threadIdx.x >> 6, lane = threadIdx.x & 63;
    int cl = lane & 15, hi = lane >> 4;
    int qbase = qt * 32;

    const bf16* Qb = Qz + (size_t)z * Nc * HDc;
    bf16x8 qf[2][2];
#pragma unroll
    for (int t = 0; t < 2; ++t) {
        const bf16* qrow = Qb + (size_t)(qbase + t * 16 + cl) * HDc + hi * 8;
        qf[t][0] = *(const bf16x8*)(qrow);
        qf[t][1] = *(const bf16x8*)(qrow + 32);
    }

    // ---- pass 1: scores for this wave's k-quarter, both tiles share K loads ----
    const bf16* Kb = Kz + ((size_t)z * Nc + wave * 128) * HDc;
    f32x4 s0[8], s1[8];
    __builtin_amdgcn_s_setprio(1);
#pragma unroll
    for (int n = 0; n < 8; ++n) {
        const bf16* krow = Kb + (n * 16 + cl) * HDc + hi * 8;
        bf16x8 k0 = *(const bf16x8*)(krow);
        bf16x8 k1 = *(const bf16x8*)(krow + 32);
        f32x4 a0 = {0.f, 0.f, 0.f, 0.f};
        a0 = __builtin_amdgcn_mfma_f32_16x16x32_bf16(k0, qf[0][0], a0, 0, 0, 0);
        a0 = __builtin_amdgcn_mfma_f32_16x16x32_bf16(k1, qf[0][1], a0, 0, 0, 0);
        s0[n] = a0;
        f32x4 a1 = {0.f, 0.f, 0.f, 0.f};
        a1 = __builtin_amdgcn_mfma_f32_16x16x32_bf16(k0, qf[1][0], a1, 0, 0, 0);
        a1 = __builtin_amdgcn_mfma_f32_16x16x32_bf16(k1, qf[1][1], a1, 0, 0, 0);
        s1[n] = a1;
    }
    __builtin_amdgcn_s_setprio(0);

    // ---- per-wave LOCAL row max (intra-wave shuffles only) ----
    f32x4 mx0 = s0[0], mx1 = s1[0];
#pragma unroll
    for (int n = 1; n < 8; ++n)
#pragma unroll
        for (int r = 0; r < 4; ++r) {
            mx0[r] = fmaxf(mx0[r], s0[n][r]);
            mx1[r] = fmaxf(mx1[r], s1[n][r]);
        }
    float mw0 = fmaxf(fmaxf(mx0[0], mx0[1]), fmaxf(mx0[2], mx0[3]));
    float mw1 = fmaxf(fmaxf(mx1[0], mx1[1]), fmaxf(mx1[2], mx1[3]));
    mw0 = fmaxf(mw0, __shfl_xor(mw0, 16)); mw0 = fmaxf(mw0, __shfl_xor(mw0, 32));
    mw1 = fmaxf(mw1, __shfl_xor(mw1, 16)); mw1 = fmaxf(mw1, __shfl_xor(mw1, 32));

    // ---- e = exp(s - m_local); local sums; deposit everything; ONE barrier ----
    f32x4 sa0 = {0.f, 0.f, 0.f, 0.f}, sa1 = {0.f, 0.f, 0.f, 0.f};
#pragma unroll
    for (int n = 0; n < 8; ++n)
#pragma unroll
        for (int r = 0; r < 4; ++r) {
            float e0 = __expf(s0[n][r] - mw0); s0[n][r] = e0; sa0[r] += e0;
            float e1 = __expf(s1[n][r] - mw1); s1[n][r] = e1; sa1[r] += e1;
        }
    float sw0 = (sa0[0] + sa0[1]) + (sa0[2] + sa0[3]);
    float sw1 = (sa1[0] + sa1[1]) + (sa1[2] + sa1[3]);
    sw0 += __shfl_xor(sw0, 16); sw0 += __shfl_xor(sw0, 32);
    sw1 += __shfl_xor(sw1, 16); sw1 += __shfl_xor(sw1, 32);
    if (lane < 16) {
        msum[0][0][wave][cl] = mw0; msum[0][1][wave][cl] = mw1;
        msum[1][0][wave][cl] = sw0; msum[1][1][wave][cl] = sw1;
    }

    char* prow0 = plds[0][cl];
    char* prow1 = plds[1][cl];
    int swz = (cl & 7) << 4;
#pragma unroll
    for (int n = 0; n < 8; ++n) {
        int off = ((wave * 4 + (n >> 1)) * 64 + hi * 16 + (n & 1) * 8) ^ swz;
        uint2 w0v = {f2bf(s0[n][0]) | (f2bf(s0[n][1]) << 16),
                     f2bf(s0[n][2]) | (f2bf(s0[n][3]) << 16)};
        uint2 w1v = {f2bf(s1[n][0]) | (f2bf(s1[n][1]) << 16),
                     f2bf(s1[n][2]) | (f2bf(s1[n][3]) << 16)};
        *(uint2*)(prow0 + off) = w0v;
        *(uint2*)(prow1 + off) = w1v;
    }

    // ---- prefetch first 12 Vp fragments (independent of LDS/barrier) ----
    const bf16* Vb = Vp + (size_t)z * 16 * 4 * 512;
    bf16x8 vpre[12];
#pragma unroll
    for (int c = 0; c < 12; ++c)
        vpre[c] = *(const bf16x8*)(Vb + ((c * 4 + wave) * 64 + lane) * 8);

    __syncthreads();    // the ONLY barrier

    // ---- global combine: m, alpha_w = exp(m_w - m), sum = sum_w sw_w*alpha_w ----
    float m0 = fmaxf(fmaxf(msum[0][0][0][cl], msum[0][0][1][cl]),
                     fmaxf(msum[0][0][2][cl], msum[0][0][3][cl]));
    float m1 = fmaxf(fmaxf(msum[0][1][0][cl], msum[0][1][1][cl]),
                     fmaxf(msum[0][1][2][cl], msum[0][1][3][cl]));
    float a00 = __expf(msum[0][0][0][cl] - m0), a01 = __expf(msum[0][0][1][cl] - m0);
    float a02 = __expf(msum[0][0][2][cl] - m0), a03 = __expf(msum[0][0][3][cl] - m0);
    float a10 = __expf(msum[0][1][0][cl] - m1), a11 = __expf(msum[0][1][1][cl] - m1);
    float a12 = __expf(msum[0][1][2][cl] - m1), a13 = __expf(msum[0][1][3][cl] - m1);
    float inv0 = 1.0f / (msum[1][0][0][cl] * a00 + msum[1][0][1][cl] * a01 +
                         msum[1][0][2][cl] * a02 + msum[1][0][3][cl] * a03);
    float inv1 = 1.0f / (msum[1][1][0][cl] * a10 + msum[1][1][1][cl] * a11 +
                         msum[1][1][2][cl] * a12 + msum[1][1][3][cl] * a13);

    // ---- attn NT stores FIRST (everything known); they drain under PV ----
    float mw0g = __expf(mw0 - m0) * inv0;
    float mw1g = __expf(mw1 - m1) * inv1;
    float* arow0 = attn + (size_t)z * Nc * Nc + (size_t)(qbase + cl) * Nc + wave * 128;
    float* arow1 = arow0 + 16 * Nc;
#pragma unroll
    for (int n = 0; n < 8; ++n) {
        f32x4 p0, p1;
#pragma unroll
        for (int r = 0; r < 4; ++r) { p0[r] = s0[n][r] * mw0g; p1[r] = s1[n][r] * mw1g; }
        __builtin_nontemporal_store(p0, (f32x4*)(arow0 + n * 16 + hi * 4));
        __builtin_nontemporal_store(p1, (f32x4*)(arow1 + n * 16 + hi * 4));
    }

    // ---- PV (d-split, split accumulators per source wave) ----
    f32x4 o0a[4], o1a[4];
#pragma unroll
    for (int w = 0; w < 4; ++w) { o0a[w] = f32x4{0.f, 0.f, 0.f, 0.f}; o1a[w] = f32x4{0.f, 0.f, 0.f, 0.f}; }
    __builtin_amdgcn_s_setprio(1);
#pragma unroll
    for (int c = 0; c < 16; ++c) {
        bf16x8 vf = (c < 12) ? vpre[c]
                             : *(const bf16x8*)(Vb + ((c * 4 + wave) * 64 + lane) * 8);
        bf16x8 pf0 = *(const bf16x8*)(prow0 + ((c * 64 + hi * 16) ^ swz));
        bf16x8 pf1 = *(const bf16x8*)(prow1 + ((c * 64 + hi * 16) ^ swz));
        o0a[c >> 2] = __builtin_amdgcn_mfma_f32_16x16x32_bf16(vf, pf0, o0a[c >> 2], 0, 0, 0);
        o1a[c >> 2] = __builtin_amdgcn_mfma_f32_16x16x32_bf16(vf, pf1, o1a[c >> 2], 0, 0, 0);
    }
    __builtin_amdgcn_s_setprio(0);
    f32x4 o0 = o0a[0] * a00 + o0a[1] * a01 + o0a[2] * a02 + o0a[3] * a03;
    f32x4 o1 = o1a[0] * a10 + o1a[1] * a11 + o1a[2] * a12 + o1a[3] * a13;

    // ---- ctx write ----
    bf16* cb0 = ctx + ((size_t)b * Nc + qbase + cl) * Dc + h * HDc + wave * 16;
    bf16* cb1 = cb0 + (size_t)16 * Dc;
    uint2 wv0 = {f2bf(o0[0] * inv0) | (f2bf(o0[1] * inv0) << 16),
                 f2bf(o0[2] * inv0) | (f2bf(o0[3] * inv0) << 16)};
    uint2 wv1 = {f2bf(o1[0] * inv1) | (f2bf(o1[1] * inv1) << 16),
                 f2bf(o1[2] * inv1) | (f2bf(o1[3] * inv1) << 16)};
    *(uint2*)(cb0 + hi * 4) = wv0;
    *(uint2*)(cb1 + hi * 4) = wv1;
}

extern "C" void kernel_launch(void* const* d_in, const int* in_sizes, int n_in,
                              void* d_out, int out_size, void* d_ws, size_t ws_size,
                              hipStream_t stream) {
    (void)in_sizes; (void)n_in; (void)out_size; (void)ws_size;
    const float* x  = (const float*)d_in[0];
    const float* g  = (const float*)d_in[1];
    const float* Wq = (const float*)d_in[2];
    const float* bq = (const float*)d_in[3];
    const float* Wk = (const float*)d_in[4];
    const float* bk = (const float*)d_in[5];
    const float* Wv = (const float*)d_in[6];
    const float* bv = (const float*)d_in[7];
    const float* Wo = (const float*)d_in[8];
    const float* bo = (const float*)d_in[9];

    float* out  = (float*)d_out;
    float* attn = out + (size_t)Bc * Nc * Dc;

    // workspace: x_bf | Wo_bf | bc | Qz Kz Vp | {Wc (phase1) / ctx (phase2)}
    char* w = (char*)d_ws;
    bf16* x_bf  = (bf16*)w;                              // 16*512*768
    bf16* Wo_bf = x_bf + (size_t)Bc * Nc * Dc;           // 768*768
    float* bc   = (float*)(Wo_bf + (size_t)Dc * Dc);     // 16*2304
    bf16* Qz    = (bf16*)(bc + (size_t)Bc * D3);         // ZS
    bf16* Kz    = Qz + ZS;                               // ZS
    bf16* Vp    = Qz + 2 * ZS;                           // ZS (fragment order)
    bf16* Wc    = Vp + ZS;                               // 16*2304*768 (phase 1)
    bf16* ctx   = Wc;                                    // overlay (phase 2)

    dim3 blk(256);

    // merged prologue: combine_w x3 | combine_b | cast Wo | cast x
    prep_kernel<<<dim3(3 * NBW + NBB + NBWO + NBX), blk, 0, stream>>>(
        g, Wq, Wk, Wv, bq, bk, bv, Wo, x, Wc, bc, Wo_bf, x_bf);

    // QKV GEMM -> compact Qz/Kz (Q pre-scaled 1/8) + direct Vp fragments
    // BM=128 BN=192: 8 XCDs x 2 z x (12 n-tiles x 4 m-tiles) = 768 blocks = 3/CU exact
    gemm_mfma<128, 192, 1, 12, 4><<<dim3(768), blk, 0, stream>>>(
        x_bf, Wc, Qz, bc, Dc, Dc, 0, Dc,
        (long)Nc * Dc, (long)D3 * Dc, 0L, D3);

    // attn (to d_out, NT) + ctx, fused: single barrier, stores-before-PV, setprio
    fused_attn_kernel<<<dim3(Bc * Hc * (Nc / 32)), blk, 0, stream>>>(Qz, Kz, Vp, attn, ctx);

    // out = ctx @ Wo^T + bo   (f32 out, NT): BM=64 -> 768 blocks, 3/CU exact
    gemm_mfma<64, 128, 0, 6, 8><<<dim3(768), blk, 0, stream>>>(
        ctx, Wo_bf, out, bo, Dc, Dc, Dc, Dc,
        (long)Nc * Dc, 0L, (long)Nc * Dc, 0);
}

// Round 19
// 165.769 us; speedup vs baseline: 1.1181x; 1.1181x over previous
//
#include <hip/hip_runtime.h>
#include <hip/hip_bf16.h>

#define Bc 16
#define Nc 512
#define Dc 768
#define Hc 12
#define Ec 8
#define HDc 64
#define D3 (3 * Dc)   // 2304
#define ZS ((size_t)Bc * Hc * Nc * HDc)   // per-tensor compact size: 192*512*64

// prep kernel block ranges
#define NBW  (Dc * Dc / 4 / 256)          // 576 blocks per weight tensor
#define NBB  (Bc * Dc / 256)              // 48
#define NBWO (Dc * Dc / 8 / 256)          // 288
#define NBX  (Bc * Nc * Dc / 8 / 256)     // 3072

typedef __hip_bfloat16 bf16;
typedef short bf16x8 __attribute__((ext_vector_type(8)));     // 8 bf16, 4 VGPR
typedef float f32x4 __attribute__((ext_vector_type(4)));
typedef unsigned short u16x4 __attribute__((ext_vector_type(4)));

__device__ __forceinline__ unsigned int f2bf(float f) {
    union { __hip_bfloat16 h; unsigned short u; } cv;
    cv.h = __float2bfloat16(f);
    return (unsigned int)cv.u;
}

__device__ __forceinline__ void gload16(const void* src, void* ldsDst) {
    __builtin_amdgcn_global_load_lds((const __attribute__((address_space(1))) void*)src,
                                     (__attribute__((address_space(3))) void*)ldsDst,
                                     16, 0, 0);
}

// ---------------- merged prologue: combine_w (x3) | combine_b | cast Wo | cast x ----------------
// (R19: reverted to plain cacheable loads/stores — R18's NT-store on Wc broke the
//  QKV GEMM's L2 reuse of the B-panel and regressed 167->185us.)
__global__ __launch_bounds__(256) void prep_kernel(const float* __restrict__ g,
                                                   const float* __restrict__ W0,
                                                   const float* __restrict__ W1,
                                                   const float* __restrict__ W2,
                                                   const float* __restrict__ b0,
                                                   const float* __restrict__ b1,
                                                   const float* __restrict__ b2,
                                                   const float* __restrict__ Wo,
                                                   const float* __restrict__ x,
                                                   bf16* __restrict__ Wc,
                                                   float* __restrict__ bc,
                                                   bf16* __restrict__ Wo_bf,
                                                   bf16* __restrict__ x_bf) {
    __shared__ float gs[Bc * Ec];
    int blk = blockIdx.x, tid = threadIdx.x;
    if (blk < 3 * NBW) {
        // ---- gating fold: Wc[b][t*768+o][i] = sum_e g[b,e] W[e][o][i] ----
        if (tid < Bc * Ec) gs[tid] = g[tid];
        __syncthreads();
        int t = blk / NBW;
        const float* W = (t == 0) ? W0 : ((t == 1) ? W1 : W2);
        int p = (blk - t * NBW) * 256 + tid;     // float4 position
        f32x4 w[Ec];
#pragma unroll
        for (int e = 0; e < Ec; ++e) w[e] = ((const f32x4*)W)[(size_t)e * (Dc * Dc / 4) + p];
        int o = p / (Dc / 4), i4 = p - o * (Dc / 4);
#pragma unroll
        for (int b = 0; b < Bc; ++b) {
            f32x4 acc = {0.f, 0.f, 0.f, 0.f};
#pragma unroll
            for (int e = 0; e < Ec; ++e) {
                float ge = gs[b * Ec + e];
                acc[0] += ge * w[e][0]; acc[1] += ge * w[e][1];
                acc[2] += ge * w[e][2]; acc[3] += ge * w[e][3];
            }
            u16x4 ov;
#pragma unroll
            for (int j = 0; j < 4; ++j) ov[j] = (unsigned short)f2bf(acc[j]);
            *(u16x4*)&Wc[((size_t)b * D3 + t * Dc + o) * Dc + i4 * 4] = ov;
        }
    } else if (blk < 3 * NBW + NBB) {
        // ---- bias fold (all three tensors per thread) ----
        int i = (blk - 3 * NBW) * 256 + tid;     // 0..Bc*Dc-1
        int b = i / Dc, o = i - b * Dc;
        const float* bs[3] = {b0, b1, b2};
#pragma unroll
        for (int t = 0; t < 3; ++t) {
            float acc = 0.f;
#pragma unroll
            for (int e = 0; e < Ec; ++e) acc += g[b * Ec + e] * bs[t][e * Dc + o];
            bc[(size_t)b * D3 + t * Dc + o] = acc;
        }
    } else if (blk < 3 * NBW + NBB + NBWO) {
        // ---- cast Wo -> bf16 ----
        int i = (blk - 3 * NBW - NBB) * 256 + tid;
        f32x4 a = ((const f32x4*)Wo)[i * 2];
        f32x4 b = ((const f32x4*)Wo)[i * 2 + 1];
        unsigned short t[8];
#pragma unroll
        for (int j = 0; j < 4; ++j) { t[j] = (unsigned short)f2bf(a[j]); t[4 + j] = (unsigned short)f2bf(b[j]); }
        ((bf16x8*)Wo_bf)[i] = *(bf16x8*)t;
    } else {
        // ---- cast x -> bf16 ----
        int i = (blk - 3 * NBW - NBB - NBWO) * 256 + tid;
        f32x4 a = ((const f32x4*)x)[i * 2];
        f32x4 b = ((const f32x4*)x)[i * 2 + 1];
        unsigned short t[8];
#pragma unroll
        for (int j = 0; j < 4; ++j) { t[j] = (unsigned short)f2bf(a[j]); t[4 + j] = (unsigned short)f2bf(b[j]); }
        ((bf16x8*)x_bf)[i] = *(bf16x8*)t;
    }
}

// ---------------- bf16 MFMA NT GEMM: C[z] = A[z] * B[z]^T (+ bias) ----------------
// R15 structure: 4 waves (2x2), tile BM x BN, BK=64 single-buffered (two 32-wide
// sub-steps per barrier pair). Grid 1-D XCD-SWIZZLED: 8 XCDs x 2 z x (NBN*NBM).
// OMODE 0: f32 output with ldc (+bias), nontemporal (write-once stream).
// OMODE 1: QKV split output -> Cout is Qz base. Q (cols<768, pre-scaled 1/8) and
//          K (768..1535) go compact [z*H+h][row][64]; V (>=1536) is written DIRECTLY
//          in Vp fragment order at +2ZS (one uint2 per m-tile).
template<int BM, int BN, int OMODE, int NBN, int NBM>
__global__ __launch_bounds__(256) void gemm_mfma(const bf16* __restrict__ Ain,
                                                 const bf16* __restrict__ Bin,
                                                 void* __restrict__ Cout,
                                                 const float* __restrict__ bias,
                                                 int lda, int ldb, int ldc, int K,
                                                 long sA, long sB, long sC, int sBias) {
    constexpr int A_LDS = BM * 128;   // two 32-col halves of BM*64 bytes each
    constexpr int B_LDS = BN * 128;
    __shared__ __align__(16) char lds[A_LDS + B_LDS];
    char* ldsA = lds;
    char* ldsB = lds + A_LDS;

    const int tid = threadIdx.x;
    const int lane = tid & 63;
    const int wave = tid >> 6;
    const int wr = wave >> 1, wc = wave & 1;
    constexpr int TM = BM / 32;
    constexpr int TN = BN / 32;

    // XCD swizzle: consecutive blockIdx round-robin XCDs (L&7).
    constexpr int PERZ = NBN * NBM;
    int L = blockIdx.x;
    int xcd = L & 7, i = L >> 3;
    int zi = (i >= PERZ) ? 1 : 0;
    const int z = xcd * 2 + zi;
    int j = i - zi * PERZ;
    const int n0 = (j % NBN) * BN;
    const int m0 = (j / NBN) * BM;

    const int mbase = wr * (BM / 2);
    const int nbase = wc * (BN / 2);

    const bf16* Ab = Ain + (size_t)z * sA;
    const bf16* Bb = Bin + (size_t)z * sB;

    f32x4 acc[TM][TN];
#pragma unroll
    for (int m = 0; m < TM; ++m)
#pragma unroll
        for (int n = 0; n < TN; ++n) acc[m][n] = f32x4{0.f, 0.f, 0.f, 0.f};

    constexpr int ACH = BM / 64;   // 1024B chunks per wave per half
    constexpr int BCH = BN / 64;

    for (int k0 = 0; k0 < K; k0 += 64) {
        // ---- stage A tile (both 32-col halves) ----
#pragma unroll
        for (int hh = 0; hh < 2; ++hh)
#pragma unroll
            for (int c = 0; c < ACH; ++c) {
                int q = wave * ACH + c;
                int row = q * 16 + (lane >> 2);
                int sl = (lane & 3) ^ (row & 3);
                const bf16* src = Ab + (size_t)(m0 + row) * lda + k0 + hh * 32 + sl * 8;
                gload16(src, ldsA + hh * (BM * 64) + q * 1024);
            }
        // ---- stage B tile ----
#pragma unroll
        for (int hh = 0; hh < 2; ++hh)
#pragma unroll
            for (int c = 0; c < BCH; ++c) {
                int q = wave * BCH + c;
                int row = q * 16 + (lane >> 2);
                int sl = (lane & 3) ^ (row & 3);
                const bf16* src = Bb + (size_t)(n0 + row) * ldb + k0 + hh * 32 + sl * 8;
                gload16(src, ldsB + hh * (BN * 64) + q * 1024);
            }
        __syncthreads();

#pragma unroll
        for (int hh = 0; hh < 2; ++hh) {
            bf16x8 af[TM], bfr[TN];
#pragma unroll
            for (int m = 0; m < TM; ++m) {
                int r = mbase + m * 16 + (lane & 15);
                int sp = (lane >> 4) ^ (lane & 3);       // == (lane>>4) ^ (r&3)
                af[m] = *(const bf16x8*)(ldsA + hh * (BM * 64) + r * 64 + sp * 16);
            }
#pragma unroll
            for (int n = 0; n < TN; ++n) {
                int r = nbase + n * 16 + (lane & 15);
                int sp = (lane >> 4) ^ (lane & 3);
                bfr[n] = *(const bf16x8*)(ldsB + hh * (BN * 64) + r * 64 + sp * 16);
            }
#pragma unroll
            for (int m = 0; m < TM; ++m)
#pragma unroll
                for (int n = 0; n < TN; ++n)
                    acc[m][n] = __builtin_amdgcn_mfma_f32_16x16x32_bf16(af[m], bfr[n], acc[m][n], 0, 0, 0);
        }
        __syncthreads();
    }

    // ---- epilogue ----
#pragma unroll
    for (int n = 0; n < TN; ++n) {
        int colbase = n0 + nbase + n * 16;
        int col = colbase + (lane & 15);
        float bv = bias ? bias[(size_t)z * sBias + col] : 0.f;
        if constexpr (OMODE == 1) {
            int t = colbase / Dc;                  // 0=Q 1=K 2=V (16-col group never crosses)
            int within = colbase - t * Dc;
            int h = within >> 6;
            int dbase = within & 63;
            if (t == 2) {
                // direct Vp fragment write: one uint2 per m-tile
                bf16* vp = (bf16*)Cout + 2 * ZS
                         + (((size_t)(z * Hc + h) * 16) * 4 + (dbase >> 4)) * 512
                         + (size_t)lane * 8;
#pragma unroll
                for (int m = 0; m < TM; ++m) {
                    int rowblk = m0 + mbase + m * 16;
                    int c = rowblk >> 5, jb = (rowblk >> 4) & 1;
                    uint2 wv = {f2bf(acc[m][n][0] + bv) | (f2bf(acc[m][n][1] + bv) << 16),
                                f2bf(acc[m][n][2] + bv) | (f2bf(acc[m][n][3] + bv) << 16)};
                    *(uint2*)(vp + (size_t)c * 2048 + jb * 4) = wv;
                }
            } else {
                float qs = (t == 0) ? 0.125f : 1.0f;
                bf16* dst = (bf16*)Cout + (size_t)t * ZS
                          + ((size_t)(z * Hc + h) * Nc) * HDc + dbase + (lane & 15);
#pragma unroll
                for (int m = 0; m < TM; ++m) {
                    int row = m0 + mbase + m * 16 + (lane >> 4) * 4;
#pragma unroll
                    for (int r = 0; r < 4; ++r)
                        dst[(size_t)(row + r) * HDc] = __float2bfloat16((acc[m][n][r] + bv) * qs);
                }
            }
        } else {
            size_t cOff = (size_t)z * sC;
#pragma unroll
            for (int m = 0; m < TM; ++m) {
                int row = m0 + mbase + m * 16 + (lane >> 4) * 4;
#pragma unroll
                for (int r = 0; r < 4; ++r)
                    __builtin_nontemporal_store(acc[m][n][r] + bv,
                        &((float*)Cout)[cOff + (size_t)(row + r) * ldc + col]);
            }
        }
    }
}

// ---------------- fused: attn[z] = softmax(Q' K^T) -> d_out; ctx = attn @ V ----------------
// Q' carries the 1/8 scale. Block = 4 waves, TWO 16-row q-tiles; k SPLIT ACROSS WAVES.
// Single-barrier flash-style combine; 8-fragment Vp prefetch across the barrier;
// attn NT stores between combine and PV; setprio around both MFMA clusters (T5).
__global__ __launch_bounds__(256) void fused_attn_kernel(const bf16* __restrict__ Qz,
                                                         const bf16* __restrict__ Kz,
                                                         const bf16* __restrict__ Vp,
                                                         float* __restrict__ attn,
                                                         bf16* __restrict__ ctx) {
    __shared__ float msum[2][2][4][16];              // [m|sum][tile][src wave][row]
    __shared__ __align__(16) char plds[2][16][1024]; // per-tile P: 16 rows x 512 k bf16

    int L = blockIdx.x;                   // 0..3071; L%8 == z%8 -> one XCD per head
    int z = (L & 7) + 8 * (L >> 7);
    int qt = (L >> 3) & 15;
    int b = z / Hc, h = z - b * Hc;
    int wave = threadIdx.x >> 6, lane = threadIdx.x & 63;
    int cl = lane & 15, hi = lane >> 4;
    int qbase = qt * 32;

    const bf16* Qb = Qz + (size_t)z * Nc * HDc;
    bf16x8 qf[2][2];
#pragma unroll
    for (int t = 0; t < 2; ++t) {
        const bf16* qrow = Qb + (size_t)(qbase + t * 16 + cl) * HDc + hi * 8;
        qf[t][0] = *(const bf16x8*)(qrow);
        qf[t][1] = *(const bf16x8*)(qrow + 32);
    }

    // ---- pass 1: scores for this wave's k-quarter, both tiles share K loads ----
    const bf16* Kb = Kz + ((size_t)z * Nc + wave * 128) * HDc;
    f32x4 s0[8], s1[8];
    __builtin_amdgcn_s_setprio(1);
#pragma unroll
    for (int n = 0; n < 8; ++n) {
        const bf16* krow = Kb + (n * 16 + cl) * HDc + hi * 8;
        bf16x8 k0 = *(const bf16x8*)(krow);
        bf16x8 k1 = *(const bf16x8*)(krow + 32);
        f32x4 a0 = {0.f, 0.f, 0.f, 0.f};
        a0 = __builtin_amdgcn_mfma_f32_16x16x32_bf16(k0, qf[0][0], a0, 0, 0, 0);
        a0 = __builtin_amdgcn_mfma_f32_16x16x32_bf16(k1, qf[0][1], a0, 0, 0, 0);
        s0[n] = a0;
        f32x4 a1 = {0.f, 0.f, 0.f, 0.f};
        a1 = __builtin_amdgcn_mfma_f32_16x16x32_bf16(k0, qf[1][0], a1, 0, 0, 0);
        a1 = __builtin_amdgcn_mfma_f32_16x16x32_bf16(k1, qf[1][1], a1, 0, 0, 0);
        s1[n] = a1;
    }
    __builtin_amdgcn_s_setprio(0);

    // ---- per-wave LOCAL row max (intra-wave shuffles only) ----
    f32x4 mx0 = s0[0], mx1 = s1[0];
#pragma unroll
    for (int n = 1; n < 8; ++n)
#pragma unroll
        for (int r = 0; r < 4; ++r) {
            mx0[r] = fmaxf(mx0[r], s0[n][r]);
            mx1[r] = fmaxf(mx1[r], s1[n][r]);
        }
    float mw0 = fmaxf(fmaxf(mx0[0], mx0[1]), fmaxf(mx0[2], mx0[3]));
    float mw1 = fmaxf(fmaxf(mx1[0], mx1[1]), fmaxf(mx1[2], mx1[3]));
    mw0 = fmaxf(mw0, __shfl_xor(mw0, 16)); mw0 = fmaxf(mw0, __shfl_xor(mw0, 32));
    mw1 = fmaxf(mw1, __shfl_xor(mw1, 16)); mw1 = fmaxf(mw1, __shfl_xor(mw1, 32));

    // ---- e = exp(s - m_local); local sums; deposit everything; ONE barrier ----
    f32x4 sa0 = {0.f, 0.f, 0.f, 0.f}, sa1 = {0.f, 0.f, 0.f, 0.f};
#pragma unroll
    for (int n = 0; n < 8; ++n)
#pragma unroll
        for (int r = 0; r < 4; ++r) {
            float e0 = __expf(s0[n][r] - mw0); s0[n][r] = e0; sa0[r] += e0;
            float e1 = __expf(s1[n][r] - mw1); s1[n][r] = e1; sa1[r] += e1;
        }
    float sw0 = (sa0[0] + sa0[1]) + (sa0[2] + sa0[3]);
    float sw1 = (sa1[0] + sa1[1]) + (sa1[2] + sa1[3]);
    sw0 += __shfl_xor(sw0, 16); sw0 += __shfl_xor(sw0, 32);
    sw1 += __shfl_xor(sw1, 16); sw1 += __shfl_xor(sw1, 32);
    if (lane < 16) {
        msum[0][0][wave][cl] = mw0; msum[0][1][wave][cl] = mw1;
        msum[1][0][wave][cl] = sw0; msum[1][1][wave][cl] = sw1;
    }

    char* prow0 = plds[0][cl];
    char* prow1 = plds[1][cl];
    int swz = (cl & 7) << 4;
#pragma unroll
    for (int n = 0; n < 8; ++n) {
        int off = ((wave * 4 + (n >> 1)) * 64 + hi * 16 + (n & 1) * 8) ^ swz;
        uint2 w0v = {f2bf(s0[n][0]) | (f2bf(s0[n][1]) << 16),
                     f2bf(s0[n][2]) | (f2bf(s0[n][3]) << 16)};
        uint2 w1v = {f2bf(s1[n][0]) | (f2bf(s1[n][1]) << 16),
                     f2bf(s1[n][2]) | (f2bf(s1[n][3]) << 16)};
        *(uint2*)(prow0 + off) = w0v;
        *(uint2*)(prow1 + off) = w1v;
    }

    // ---- prefetch first 8 Vp fragments (independent of LDS/barrier) ----
    const bf16* Vb = Vp + (size_t)z * 16 * 4 * 512;
    bf16x8 vpre[8];
#pragma unroll
    for (int c = 0; c < 8; ++c)
        vpre[c] = *(const bf16x8*)(Vb + ((c * 4 + wave) * 64 + lane) * 8);

    __syncthreads();    // the ONLY barrier

    // ---- global combine: m, alpha_w = exp(m_w - m), sum = sum_w sw_w*alpha_w ----
    float m0 = fmaxf(fmaxf(msum[0][0][0][cl], msum[0][0][1][cl]),
                     fmaxf(msum[0][0][2][cl], msum[0][0][3][cl]));
    float m1 = fmaxf(fmaxf(msum[0][1][0][cl], msum[0][1][1][cl]),
                     fmaxf(msum[0][1][2][cl], msum[0][1][3][cl]));
    float a00 = __expf(msum[0][0][0][cl] - m0), a01 = __expf(msum[0][0][1][cl] - m0);
    float a02 = __expf(msum[0][0][2][cl] - m0), a03 = __expf(msum[0][0][3][cl] - m0);
    float a10 = __expf(msum[0][1][0][cl] - m1), a11 = __expf(msum[0][1][1][cl] - m1);
    float a12 = __expf(msum[0][1][2][cl] - m1), a13 = __expf(msum[0][1][3][cl] - m1);
    float inv0 = 1.0f / (msum[1][0][0][cl] * a00 + msum[1][0][1][cl] * a01 +
                         msum[1][0][2][cl] * a02 + msum[1][0][3][cl] * a03);
    float inv1 = 1.0f / (msum[1][1][0][cl] * a10 + msum[1][1][1][cl] * a11 +
                         msum[1][1][2][cl] * a12 + msum[1][1][3][cl] * a13);

    // ---- attn NT stores FIRST (everything known); they drain under PV ----
    float mw0g = __expf(mw0 - m0) * inv0;
    float mw1g = __expf(mw1 - m1) * inv1;
    float* arow0 = attn + (size_t)z * Nc * Nc + (size_t)(qbase + cl) * Nc + wave * 128;
    float* arow1 = arow0 + 16 * Nc;
#pragma unroll
    for (int n = 0; n < 8; ++n) {
        f32x4 p0, p1;
#pragma unroll
        for (int r = 0; r < 4; ++r) { p0[r] = s0[n][r] * mw0g; p1[r] = s1[n][r] * mw1g; }
        __builtin_nontemporal_store(p0, (f32x4*)(arow0 + n * 16 + hi * 4));
        __builtin_nontemporal_store(p1, (f32x4*)(arow1 + n * 16 + hi * 4));
    }

    // ---- PV (d-split, split accumulators per source wave) ----
    f32x4 o0a[4], o1a[4];
#pragma unroll
    for (int w = 0; w < 4; ++w) { o0a[w] = f32x4{0.f, 0.f, 0.f, 0.f}; o1a[w] = f32x4{0.f, 0.f, 0.f, 0.f}; }
    __builtin_amdgcn_s_setprio(1);
#pragma unroll
    for (int c = 0; c < 16; ++c) {
        bf16x8 vf = (c < 8) ? vpre[c]
                            : *(const bf16x8*)(Vb + ((c * 4 + wave) * 64 + lane) * 8);
        bf16x8 pf0 = *(const bf16x8*)(prow0 + ((c * 64 + hi * 16) ^ swz));
        bf16x8 pf1 = *(const bf16x8*)(prow1 + ((c * 64 + hi * 16) ^ swz));
        o0a[c >> 2] = __builtin_amdgcn_mfma_f32_16x16x32_bf16(vf, pf0, o0a[c >> 2], 0, 0, 0);
        o1a[c >> 2] = __builtin_amdgcn_mfma_f32_16x16x32_bf16(vf, pf1, o1a[c >> 2], 0, 0, 0);
    }
    __builtin_amdgcn_s_setprio(0);
    f32x4 o0 = o0a[0] * a00 + o0a[1] * a01 + o0a[2] * a02 + o0a[3] * a03;
    f32x4 o1 = o1a[0] * a10 + o1a[1] * a11 + o1a[2] * a12 + o1a[3] * a13;

    // ---- ctx write ----
    bf16* cb0 = ctx + ((size_t)b * Nc + qbase + cl) * Dc + h * HDc + wave * 16;
    bf16* cb1 = cb0 + (size_t)16 * Dc;
    uint2 wv0 = {f2bf(o0[0] * inv0) | (f2bf(o0[1] * inv0) << 16),
                 f2bf(o0[2] * inv0) | (f2bf(o0[3] * inv0) << 16)};
    uint2 wv1 = {f2bf(o1[0] * inv1) | (f2bf(o1[1] * inv1) << 16),
                 f2bf(o1[2] * inv1) | (f2bf(o1[3] * inv1) << 16)};
    *(uint2*)(cb0 + hi * 4) = wv0;
    *(uint2*)(cb1 + hi * 4) = wv1;
}

extern "C" void kernel_launch(void* const* d_in, const int* in_sizes, int n_in,
                              void* d_out, int out_size, void* d_ws, size_t ws_size,
                              hipStream_t stream) {
    (void)in_sizes; (void)n_in; (void)out_size; (void)ws_size;
    const float* x  = (const float*)d_in[0];
    const float* g  = (const float*)d_in[1];
    const float* Wq = (const float*)d_in[2];
    const float* bq = (const float*)d_in[3];
    const float* Wk = (const float*)d_in[4];
    const float* bk = (const float*)d_in[5];
    const float* Wv = (const float*)d_in[6];
    const float* bv = (const float*)d_in[7];
    const float* Wo = (const float*)d_in[8];
    const float* bo = (const float*)d_in[9];

    float* out  = (float*)d_out;
    float* attn = out + (size_t)Bc * Nc * Dc;

    // workspace: x_bf | Wo_bf | bc | Qz Kz Vp | {Wc (phase1) / ctx (phase2)}
    char* w = (char*)d_ws;
    bf16* x_bf  = (bf16*)w;                              // 16*512*768
    bf16* Wo_bf = x_bf + (size_t)Bc * Nc * Dc;           // 768*768
    float* bc   = (float*)(Wo_bf + (size_t)Dc * Dc);     // 16*2304
    bf16* Qz    = (bf16*)(bc + (size_t)Bc * D3);         // ZS
    bf16* Kz    = Qz + ZS;                               // ZS
    bf16* Vp    = Qz + 2 * ZS;                           // ZS (fragment order)
    bf16* Wc    = Vp + ZS;                               // 16*2304*768 (phase 1)
    bf16* ctx   = Wc;                                    // overlay (phase 2)

    dim3 blk(256);

    // merged prologue: combine_w x3 | combine_b | cast Wo | cast x
    prep_kernel<<<dim3(3 * NBW + NBB + NBWO + NBX), blk, 0, stream>>>(
        g, Wq, Wk, Wv, bq, bk, bv, Wo, x, Wc, bc, Wo_bf, x_bf);

    // QKV GEMM -> compact Qz/Kz (Q pre-scaled 1/8) + direct Vp fragments
    // BM=128 BN=192: 8 XCDs x 2 z x (12 n-tiles x 4 m-tiles) = 768 blocks = 3/CU exact
    gemm_mfma<128, 192, 1, 12, 4><<<dim3(768), blk, 0, stream>>>(
        x_bf, Wc, Qz, bc, Dc, Dc, 0, Dc,
        (long)Nc * Dc, (long)D3 * Dc, 0L, D3);

    // attn (to d_out, NT) + ctx, fused: single barrier, stores-before-PV, setprio
    fused_attn_kernel<<<dim3(Bc * Hc * (Nc / 32)), blk, 0, stream>>>(Qz, Kz, Vp, attn, ctx);

    // out = ctx @ Wo^T + bo   (f32 out, NT): BM=64 -> 768 blocks, 3/CU exact
    gemm_mfma<64, 128, 0, 6, 8><<<dim3(768), blk, 0, stream>>>(
        ctx, Wo_bf, out, bo, Dc, Dc, Dc, Dc,
        (long)Nc * Dc, 0L, (long)Nc * Dc, 0);
}

// Round 20
// 165.521 us; speedup vs baseline: 1.1198x; 1.0015x over previous
//
#include <hip/hip_runtime.h>
#include <hip/hip_bf16.h>

#define Bc 16
#define Nc 512
#define Dc 768
#define Hc 12
#define Ec 8
#define HDc 64
#define D3 (3 * Dc)   // 2304
#define ZS ((size_t)Bc * Hc * Nc * HDc)   // per-tensor compact size: 192*512*64

// prep kernel block ranges
#define NBW8 (Dc * Dc / 8 / 256)          // 288 blocks per weight tensor (8 elems/thread)
#define NBB  (Bc * Dc / 256)              // 48
#define NBWO (Dc * Dc / 8 / 256)          // 288
#define NBX  (Bc * Nc * Dc / 8 / 256)     // 3072

typedef __hip_bfloat16 bf16;
typedef short bf16x8 __attribute__((ext_vector_type(8)));     // 8 bf16, 4 VGPR
typedef float f32x4 __attribute__((ext_vector_type(4)));
typedef unsigned short u16x4 __attribute__((ext_vector_type(4)));

__device__ __forceinline__ unsigned int f2bf(float f) {
    union { __hip_bfloat16 h; unsigned short u; } cv;
    cv.h = __float2bfloat16(f);
    return (unsigned int)cv.u;
}

__device__ __forceinline__ void gload16(const void* src, void* ldsDst) {
    __builtin_amdgcn_global_load_lds((const __attribute__((address_space(1))) void*)src,
                                     (__attribute__((address_space(3))) void*)ldsDst,
                                     16, 0, 0);
}

// ---------------- merged prologue: combine_w (x3) | combine_b | cast Wo | cast x ----------------
// R20: combine_w widened to 8 elems/thread -> 16B bf16x8 stores (full-width wave
// stores, half the store count; 864 fold blocks instead of 1728). Plain cacheable
// loads/stores throughout (R18's NT experiment regressed).
__global__ __launch_bounds__(256) void prep_kernel(const float* __restrict__ g,
                                                   const float* __restrict__ W0,
                                                   const float* __restrict__ W1,
                                                   const float* __restrict__ W2,
                                                   const float* __restrict__ b0,
                                                   const float* __restrict__ b1,
                                                   const float* __restrict__ b2,
                                                   const float* __restrict__ Wo,
                                                   const float* __restrict__ x,
                                                   bf16* __restrict__ Wc,
                                                   float* __restrict__ bc,
                                                   bf16* __restrict__ Wo_bf,
                                                   bf16* __restrict__ x_bf) {
    __shared__ float gs[Bc * Ec];
    int blk = blockIdx.x, tid = threadIdx.x;
    if (blk < 3 * NBW8) {
        // ---- gating fold: Wc[b][t*768+o][i] = sum_e g[b,e] W[e][o][i], 8 elems/thread ----
        if (tid < Bc * Ec) gs[tid] = g[tid];
        __syncthreads();
        int t = blk / NBW8;
        const float* W = (t == 0) ? W0 : ((t == 1) ? W1 : W2);
        int p = (blk - t * NBW8) * 256 + tid;    // 8-elem position
        f32x4 w[Ec][2];
#pragma unroll
        for (int e = 0; e < Ec; ++e) {
            const f32x4* base = (const f32x4*)W + (size_t)e * (Dc * Dc / 4) + p * 2;
            w[e][0] = base[0];
            w[e][1] = base[1];
        }
        int o = p / (Dc / 8), i8 = p - o * (Dc / 8);
#pragma unroll
        for (int b = 0; b < Bc; ++b) {
            unsigned short tv[8];
#pragma unroll
            for (int hh = 0; hh < 2; ++hh) {
                f32x4 acc = {0.f, 0.f, 0.f, 0.f};
#pragma unroll
                for (int e = 0; e < Ec; ++e) {
                    float ge = gs[b * Ec + e];
                    acc[0] += ge * w[e][hh][0]; acc[1] += ge * w[e][hh][1];
                    acc[2] += ge * w[e][hh][2]; acc[3] += ge * w[e][hh][3];
                }
#pragma unroll
                for (int j = 0; j < 4; ++j) tv[hh * 4 + j] = (unsigned short)f2bf(acc[j]);
            }
            *(bf16x8*)&Wc[((size_t)b * D3 + t * Dc + o) * Dc + i8 * 8] = *(bf16x8*)tv;
        }
    } else if (blk < 3 * NBW8 + NBB) {
        // ---- bias fold (all three tensors per thread) ----
        int i = (blk - 3 * NBW8) * 256 + tid;    // 0..Bc*Dc-1
        int b = i / Dc, o = i - b * Dc;
        const float* bs[3] = {b0, b1, b2};
#pragma unroll
        for (int t = 0; t < 3; ++t) {
            float acc = 0.f;
#pragma unroll
            for (int e = 0; e < Ec; ++e) acc += g[b * Ec + e] * bs[t][e * Dc + o];
            bc[(size_t)b * D3 + t * Dc + o] = acc;
        }
    } else if (blk < 3 * NBW8 + NBB + NBWO) {
        // ---- cast Wo -> bf16 ----
        int i = (blk - 3 * NBW8 - NBB) * 256 + tid;
        f32x4 a = ((const f32x4*)Wo)[i * 2];
        f32x4 b = ((const f32x4*)Wo)[i * 2 + 1];
        unsigned short t[8];
#pragma unroll
        for (int j = 0; j < 4; ++j) { t[j] = (unsigned short)f2bf(a[j]); t[4 + j] = (unsigned short)f2bf(b[j]); }
        ((bf16x8*)Wo_bf)[i] = *(bf16x8*)t;
    } else {
        // ---- cast x -> bf16 ----
        int i = (blk - 3 * NBW8 - NBB - NBWO) * 256 + tid;
        f32x4 a = ((const f32x4*)x)[i * 2];
        f32x4 b = ((const f32x4*)x)[i * 2 + 1];
        unsigned short t[8];
#pragma unroll
        for (int j = 0; j < 4; ++j) { t[j] = (unsigned short)f2bf(a[j]); t[4 + j] = (unsigned short)f2bf(b[j]); }
        ((bf16x8*)x_bf)[i] = *(bf16x8*)t;
    }
}

// ---------------- bf16 MFMA NT GEMM: C[z] = A[z] * B[z]^T (+ bias) ----------------
// R15 structure: 4 waves (2x2), tile BM x BN, BK=64 single-buffered (two 32-wide
// sub-steps per barrier pair). Grid 1-D XCD-SWIZZLED: 8 XCDs x 2 z x (NBN*NBM).
// OMODE 0: f32 output with ldc (+bias), nontemporal (write-once stream).
// OMODE 1: QKV split output -> Cout is Qz base. Q (cols<768, pre-scaled 1/8) and
//          K (768..1535) go compact [z*H+h][row][64]; V (>=1536) is written DIRECTLY
//          in Vp fragment order at +2ZS (one uint2 per m-tile).
template<int BM, int BN, int OMODE, int NBN, int NBM>
__global__ __launch_bounds__(256) void gemm_mfma(const bf16* __restrict__ Ain,
                                                 const bf16* __restrict__ Bin,
                                                 void* __restrict__ Cout,
                                                 const float* __restrict__ bias,
                                                 int lda, int ldb, int ldc, int K,
                                                 long sA, long sB, long sC, int sBias) {
    constexpr int A_LDS = BM * 128;   // two 32-col halves of BM*64 bytes each
    constexpr int B_LDS = BN * 128;
    __shared__ __align__(16) char lds[A_LDS + B_LDS];
    char* ldsA = lds;
    char* ldsB = lds + A_LDS;

    const int tid = threadIdx.x;
    const int lane = tid & 63;
    const int wave = tid >> 6;
    const int wr = wave >> 1, wc = wave & 1;
    constexpr int TM = BM / 32;
    constexpr int TN = BN / 32;

    // XCD swizzle: consecutive blockIdx round-robin XCDs (L&7).
    constexpr int PERZ = NBN * NBM;
    int L = blockIdx.x;
    int xcd = L & 7, i = L >> 3;
    int zi = (i >= PERZ) ? 1 : 0;
    const int z = xcd * 2 + zi;
    int j = i - zi * PERZ;
    const int n0 = (j % NBN) * BN;
    const int m0 = (j / NBN) * BM;

    const int mbase = wr * (BM / 2);
    const int nbase = wc * (BN / 2);

    const bf16* Ab = Ain + (size_t)z * sA;
    const bf16* Bb = Bin + (size_t)z * sB;

    f32x4 acc[TM][TN];
#pragma unroll
    for (int m = 0; m < TM; ++m)
#pragma unroll
        for (int n = 0; n < TN; ++n) acc[m][n] = f32x4{0.f, 0.f, 0.f, 0.f};

    constexpr int ACH = BM / 64;   // 1024B chunks per wave per half
    constexpr int BCH = BN / 64;

    for (int k0 = 0; k0 < K; k0 += 64) {
        // ---- stage A tile (both 32-col halves) ----
#pragma unroll
        for (int hh = 0; hh < 2; ++hh)
#pragma unroll
            for (int c = 0; c < ACH; ++c) {
                int q = wave * ACH + c;
                int row = q * 16 + (lane >> 2);
                int sl = (lane & 3) ^ (row & 3);
                const bf16* src = Ab + (size_t)(m0 + row) * lda + k0 + hh * 32 + sl * 8;
                gload16(src, ldsA + hh * (BM * 64) + q * 1024);
            }
        // ---- stage B tile ----
#pragma unroll
        for (int hh = 0; hh < 2; ++hh)
#pragma unroll
            for (int c = 0; c < BCH; ++c) {
                int q = wave * BCH + c;
                int row = q * 16 + (lane >> 2);
                int sl = (lane & 3) ^ (row & 3);
                const bf16* src = Bb + (size_t)(n0 + row) * ldb + k0 + hh * 32 + sl * 8;
                gload16(src, ldsB + hh * (BN * 64) + q * 1024);
            }
        __syncthreads();

#pragma unroll
        for (int hh = 0; hh < 2; ++hh) {
            bf16x8 af[TM], bfr[TN];
#pragma unroll
            for (int m = 0; m < TM; ++m) {
                int r = mbase + m * 16 + (lane & 15);
                int sp = (lane >> 4) ^ (lane & 3);       // == (lane>>4) ^ (r&3)
                af[m] = *(const bf16x8*)(ldsA + hh * (BM * 64) + r * 64 + sp * 16);
            }
#pragma unroll
            for (int n = 0; n < TN; ++n) {
                int r = nbase + n * 16 + (lane & 15);
                int sp = (lane >> 4) ^ (lane & 3);
                bfr[n] = *(const bf16x8*)(ldsB + hh * (BN * 64) + r * 64 + sp * 16);
            }
#pragma unroll
            for (int m = 0; m < TM; ++m)
#pragma unroll
                for (int n = 0; n < TN; ++n)
                    acc[m][n] = __builtin_amdgcn_mfma_f32_16x16x32_bf16(af[m], bfr[n], acc[m][n], 0, 0, 0);
        }
        __syncthreads();
    }

    // ---- epilogue ----
#pragma unroll
    for (int n = 0; n < TN; ++n) {
        int colbase = n0 + nbase + n * 16;
        int col = colbase + (lane & 15);
        float bv = bias ? bias[(size_t)z * sBias + col] : 0.f;
        if constexpr (OMODE == 1) {
            int t = colbase / Dc;                  // 0=Q 1=K 2=V (16-col group never crosses)
            int within = colbase - t * Dc;
            int h = within >> 6;
            int dbase = within & 63;
            if (t == 2) {
                // direct Vp fragment write: one uint2 per m-tile
                bf16* vp = (bf16*)Cout + 2 * ZS
                         + (((size_t)(z * Hc + h) * 16) * 4 + (dbase >> 4)) * 512
                         + (size_t)lane * 8;
#pragma unroll
                for (int m = 0; m < TM; ++m) {
                    int rowblk = m0 + mbase + m * 16;
                    int c = rowblk >> 5, jb = (rowblk >> 4) & 1;
                    uint2 wv = {f2bf(acc[m][n][0] + bv) | (f2bf(acc[m][n][1] + bv) << 16),
                                f2bf(acc[m][n][2] + bv) | (f2bf(acc[m][n][3] + bv) << 16)};
                    *(uint2*)(vp + (size_t)c * 2048 + jb * 4) = wv;
                }
            } else {
                float qs = (t == 0) ? 0.125f : 1.0f;
                bf16* dst = (bf16*)Cout + (size_t)t * ZS
                          + ((size_t)(z * Hc + h) * Nc) * HDc + dbase + (lane & 15);
#pragma unroll
                for (int m = 0; m < TM; ++m) {
                    int row = m0 + mbase + m * 16 + (lane >> 4) * 4;
#pragma unroll
                    for (int r = 0; r < 4; ++r)
                        dst[(size_t)(row + r) * HDc] = __float2bfloat16((acc[m][n][r] + bv) * qs);
                }
            }
        } else {
            size_t cOff = (size_t)z * sC;
#pragma unroll
            for (int m = 0; m < TM; ++m) {
                int row = m0 + mbase + m * 16 + (lane >> 4) * 4;
#pragma unroll
                for (int r = 0; r < 4; ++r)
                    __builtin_nontemporal_store(acc[m][n][r] + bv,
                        &((float*)Cout)[cOff + (size_t)(row + r) * ldc + col]);
            }
        }
    }
}

// ---------------- fused: attn[z] = softmax(Q' K^T) -> d_out; ctx = attn @ V ----------------
// Q' carries the 1/8 scale. Block = 4 waves, TWO 16-row q-tiles; k SPLIT ACROSS WAVES.
// Single-barrier flash-style combine; 8-fragment Vp prefetch across the barrier;
// attn NT stores between combine and PV; setprio around both MFMA clusters (T5).
__global__ __launch_bounds__(256) void fused_attn_kernel(const bf16* __restrict__ Qz,
                                                         const bf16* __restrict__ Kz,
                                                         const bf16* __restrict__ Vp,
                                                         float* __restrict__ attn,
                                                         bf16* __restrict__ ctx) {
    __shared__ float msum[2][2][4][16];              // [m|sum][tile][src wave][row]
    __shared__ __align__(16) char plds[2][16][1024]; // per-tile P: 16 rows x 512 k bf16

    int L = blockIdx.x;                   // 0..3071; L%8 == z%8 -> one XCD per head
    int z = (L & 7) + 8 * (L >> 7);
    int qt = (L >> 3) & 15;
    int b = z / Hc, h = z - b * Hc;
    int wave = threadIdx.x >> 6, lane = threadIdx.x & 63;
    int cl = lane & 15, hi = lane >> 4;
    int qbase = qt * 32;

    const bf16* Qb = Qz + (size_t)z * Nc * HDc;
    bf16x8 qf[2][2];
#pragma unroll
    for (int t = 0; t < 2; ++t) {
        const bf16* qrow = Qb + (size_t)(qbase + t * 16 + cl) * HDc + hi * 8;
        qf[t][0] = *(const bf16x8*)(qrow);
        qf[t][1] = *(const bf16x8*)(qrow + 32);
    }

    // ---- pass 1: scores for this wave's k-quarter, both tiles share K loads ----
    const bf16* Kb = Kz + ((size_t)z * Nc + wave * 128) * HDc;
    f32x4 s0[8], s1[8];
    __builtin_amdgcn_s_setprio(1);
#pragma unroll
    for (int n = 0; n < 8; ++n) {
        const bf16* krow = Kb + (n * 16 + cl) * HDc + hi * 8;
        bf16x8 k0 = *(const bf16x8*)(krow);
        bf16x8 k1 = *(const bf16x8*)(krow + 32);
        f32x4 a0 = {0.f, 0.f, 0.f, 0.f};
        a0 = __builtin_amdgcn_mfma_f32_16x16x32_bf16(k0, qf[0][0], a0, 0, 0, 0);
        a0 = __builtin_amdgcn_mfma_f32_16x16x32_bf16(k1, qf[0][1], a0, 0, 0, 0);
        s0[n] = a0;
        f32x4 a1 = {0.f, 0.f, 0.f, 0.f};
        a1 = __builtin_amdgcn_mfma_f32_16x16x32_bf16(k0, qf[1][0], a1, 0, 0, 0);
        a1 = __builtin_amdgcn_mfma_f32_16x16x32_bf16(k1, qf[1][1], a1, 0, 0, 0);
        s1[n] = a1;
    }
    __builtin_amdgcn_s_setprio(0);

    // ---- per-wave LOCAL row max (intra-wave shuffles only) ----
    f32x4 mx0 = s0[0], mx1 = s1[0];
#pragma unroll
    for (int n = 1; n < 8; ++n)
#pragma unroll
        for (int r = 0; r < 4; ++r) {
            mx0[r] = fmaxf(mx0[r], s0[n][r]);
            mx1[r] = fmaxf(mx1[r], s1[n][r]);
        }
    float mw0 = fmaxf(fmaxf(mx0[0], mx0[1]), fmaxf(mx0[2], mx0[3]));
    float mw1 = fmaxf(fmaxf(mx1[0], mx1[1]), fmaxf(mx1[2], mx1[3]));
    mw0 = fmaxf(mw0, __shfl_xor(mw0, 16)); mw0 = fmaxf(mw0, __shfl_xor(mw0, 32));
    mw1 = fmaxf(mw1, __shfl_xor(mw1, 16)); mw1 = fmaxf(mw1, __shfl_xor(mw1, 32));

    // ---- e = exp(s - m_local); local sums; deposit everything; ONE barrier ----
    f32x4 sa0 = {0.f, 0.f, 0.f, 0.f}, sa1 = {0.f, 0.f, 0.f, 0.f};
#pragma unroll
    for (int n = 0; n < 8; ++n)
#pragma unroll
        for (int r = 0; r < 4; ++r) {
            float e0 = __expf(s0[n][r] - mw0); s0[n][r] = e0; sa0[r] += e0;
            float e1 = __expf(s1[n][r] - mw1); s1[n][r] = e1; sa1[r] += e1;
        }
    float sw0 = (sa0[0] + sa0[1]) + (sa0[2] + sa0[3]);
    float sw1 = (sa1[0] + sa1[1]) + (sa1[2] + sa1[3]);
    sw0 += __shfl_xor(sw0, 16); sw0 += __shfl_xor(sw0, 32);
    sw1 += __shfl_xor(sw1, 16); sw1 += __shfl_xor(sw1, 32);
    if (lane < 16) {
        msum[0][0][wave][cl] = mw0; msum[0][1][wave][cl] = mw1;
        msum[1][0][wave][cl] = sw0; msum[1][1][wave][cl] = sw1;
    }

    char* prow0 = plds[0][cl];
    char* prow1 = plds[1][cl];
    int swz = (cl & 7) << 4;
#pragma unroll
    for (int n = 0; n < 8; ++n) {
        int off = ((wave * 4 + (n >> 1)) * 64 + hi * 16 + (n & 1) * 8) ^ swz;
        uint2 w0v = {f2bf(s0[n][0]) | (f2bf(s0[n][1]) << 16),
                     f2bf(s0[n][2]) | (f2bf(s0[n][3]) << 16)};
        uint2 w1v = {f2bf(s1[n][0]) | (f2bf(s1[n][1]) << 16),
                     f2bf(s1[n][2]) | (f2bf(s1[n][3]) << 16)};
        *(uint2*)(prow0 + off) = w0v;
        *(uint2*)(prow1 + off) = w1v;
    }

    // ---- prefetch first 8 Vp fragments (independent of LDS/barrier) ----
    const bf16* Vb = Vp + (size_t)z * 16 * 4 * 512;
    bf16x8 vpre[8];
#pragma unroll
    for (int c = 0; c < 8; ++c)
        vpre[c] = *(const bf16x8*)(Vb + ((c * 4 + wave) * 64 + lane) * 8);

    __syncthreads();    // the ONLY barrier

    // ---- global combine: m, alpha_w = exp(m_w - m), sum = sum_w sw_w*alpha_w ----
    float m0 = fmaxf(fmaxf(msum[0][0][0][cl], msum[0][0][1][cl]),
                     fmaxf(msum[0][0][2][cl], msum[0][0][3][cl]));
    float m1 = fmaxf(fmaxf(msum[0][1][0][cl], msum[0][1][1][cl]),
                     fmaxf(msum[0][1][2][cl], msum[0][1][3][cl]));
    float a00 = __expf(msum[0][0][0][cl] - m0), a01 = __expf(msum[0][0][1][cl] - m0);
    float a02 = __expf(msum[0][0][2][cl] - m0), a03 = __expf(msum[0][0][3][cl] - m0);
    float a10 = __expf(msum[0][1][0][cl] - m1), a11 = __expf(msum[0][1][1][cl] - m1);
    float a12 = __expf(msum[0][1][2][cl] - m1), a13 = __expf(msum[0][1][3][cl] - m1);
    float inv0 = 1.0f / (msum[1][0][0][cl] * a00 + msum[1][0][1][cl] * a01 +
                         msum[1][0][2][cl] * a02 + msum[1][0][3][cl] * a03);
    float inv1 = 1.0f / (msum[1][1][0][cl] * a10 + msum[1][1][1][cl] * a11 +
                         msum[1][1][2][cl] * a12 + msum[1][1][3][cl] * a13);

    // ---- attn NT stores FIRST (everything known); they drain under PV ----
    float mw0g = __expf(mw0 - m0) * inv0;
    float mw1g = __expf(mw1 - m1) * inv1;
    float* arow0 = attn + (size_t)z * Nc * Nc + (size_t)(qbase + cl) * Nc + wave * 128;
    float* arow1 = arow0 + 16 * Nc;
#pragma unroll
    for (int n = 0; n < 8; ++n) {
        f32x4 p0, p1;
#pragma unroll
        for (int r = 0; r < 4; ++r) { p0[r] = s0[n][r] * mw0g; p1[r] = s1[n][r] * mw1g; }
        __builtin_nontemporal_store(p0, (f32x4*)(arow0 + n * 16 + hi * 4));
        __builtin_nontemporal_store(p1, (f32x4*)(arow1 + n * 16 + hi * 4));
    }

    // ---- PV (d-split, split accumulators per source wave) ----
    f32x4 o0a[4], o1a[4];
#pragma unroll
    for (int w = 0; w < 4; ++w) { o0a[w] = f32x4{0.f, 0.f, 0.f, 0.f}; o1a[w] = f32x4{0.f, 0.f, 0.f, 0.f}; }
    __builtin_amdgcn_s_setprio(1);
#pragma unroll
    for (int c = 0; c < 16; ++c) {
        bf16x8 vf = (c < 8) ? vpre[c]
                            : *(const bf16x8*)(Vb + ((c * 4 + wave) * 64 + lane) * 8);
        bf16x8 pf0 = *(const bf16x8*)(prow0 + ((c * 64 + hi * 16) ^ swz));
        bf16x8 pf1 = *(const bf16x8*)(prow1 + ((c * 64 + hi * 16) ^ swz));
        o0a[c >> 2] = __builtin_amdgcn_mfma_f32_16x16x32_bf16(vf, pf0, o0a[c >> 2], 0, 0, 0);
        o1a[c >> 2] = __builtin_amdgcn_mfma_f32_16x16x32_bf16(vf, pf1, o1a[c >> 2], 0, 0, 0);
    }
    __builtin_amdgcn_s_setprio(0);
    f32x4 o0 = o0a[0] * a00 + o0a[1] * a01 + o0a[2] * a02 + o0a[3] * a03;
    f32x4 o1 = o1a[0] * a10 + o1a[1] * a11 + o1a[2] * a12 + o1a[3] * a13;

    // ---- ctx write ----
    bf16* cb0 = ctx + ((size_t)b * Nc + qbase + cl) * Dc + h * HDc + wave * 16;
    bf16* cb1 = cb0 + (size_t)16 * Dc;
    uint2 wv0 = {f2bf(o0[0] * inv0) | (f2bf(o0[1] * inv0) << 16),
                 f2bf(o0[2] * inv0) | (f2bf(o0[3] * inv0) << 16)};
    uint2 wv1 = {f2bf(o1[0] * inv1) | (f2bf(o1[1] * inv1) << 16),
                 f2bf(o1[2] * inv1) | (f2bf(o1[3] * inv1) << 16)};
    *(uint2*)(cb0 + hi * 4) = wv0;
    *(uint2*)(cb1 + hi * 4) = wv1;
}

extern "C" void kernel_launch(void* const* d_in, const int* in_sizes, int n_in,
                              void* d_out, int out_size, void* d_ws, size_t ws_size,
                              hipStream_t stream) {
    (void)in_sizes; (void)n_in; (void)out_size; (void)ws_size;
    const float* x  = (const float*)d_in[0];
    const float* g  = (const float*)d_in[1];
    const float* Wq = (const float*)d_in[2];
    const float* bq = (const float*)d_in[3];
    const float* Wk = (const float*)d_in[4];
    const float* bk = (const float*)d_in[5];
    const float* Wv = (const float*)d_in[6];
    const float* bv = (const float*)d_in[7];
    const float* Wo = (const float*)d_in[8];
    const float* bo = (const float*)d_in[9];

    float* out  = (float*)d_out;
    float* attn = out + (size_t)Bc * Nc * Dc;

    // workspace: x_bf | Wo_bf | bc | Qz Kz Vp | {Wc (phase1) / ctx (phase2)}
    char* w = (char*)d_ws;
    bf16* x_bf  = (bf16*)w;                              // 16*512*768
    bf16* Wo_bf = x_bf + (size_t)Bc * Nc * Dc;           // 768*768
    float* bc   = (float*)(Wo_bf + (size_t)Dc * Dc);     // 16*2304
    bf16* Qz    = (bf16*)(bc + (size_t)Bc * D3);         // ZS
    bf16* Kz    = Qz + ZS;                               // ZS
    bf16* Vp    = Qz + 2 * ZS;                           // ZS (fragment order)
    bf16* Wc    = Vp + ZS;                               // 16*2304*768 (phase 1)
    bf16* ctx   = Wc;                                    // overlay (phase 2)

    dim3 blk(256);

    // merged prologue: combine_w x3 (8 elems/thread) | combine_b | cast Wo | cast x
    prep_kernel<<<dim3(3 * NBW8 + NBB + NBWO + NBX), blk, 0, stream>>>(
        g, Wq, Wk, Wv, bq, bk, bv, Wo, x, Wc, bc, Wo_bf, x_bf);

    // QKV GEMM -> compact Qz/Kz (Q pre-scaled 1/8) + direct Vp fragments
    // BM=128 BN=192: 8 XCDs x 2 z x (12 n-tiles x 4 m-tiles) = 768 blocks = 3/CU exact
    gemm_mfma<128, 192, 1, 12, 4><<<dim3(768), blk, 0, stream>>>(
        x_bf, Wc, Qz, bc, Dc, Dc, 0, Dc,
        (long)Nc * Dc, (long)D3 * Dc, 0L, D3);

    // attn (to d_out, NT) + ctx, fused: single barrier, stores-before-PV, setprio
    fused_attn_kernel<<<dim3(Bc * Hc * (Nc / 32)), blk, 0, stream>>>(Qz, Kz, Vp, attn, ctx);

    // out = ctx @ Wo^T + bo   (f32 out, NT): BM=64 -> 768 blocks, 3/CU exact
    gemm_mfma<64, 128, 0, 6, 8><<<dim3(768), blk, 0, stream>>>(
        ctx, Wo_bf, out, bo, Dc, Dc, Dc, Dc,
        (long)Nc * Dc, 0L, (long)Nc * Dc, 0);
}